// Round 2
// baseline (278.197 us; speedup 1.0000x reference)
//
#include <hip/hip_runtime.h>

typedef __attribute__((ext_vector_type(8))) short s8v;   // 8 x bf16 (4 VGPRs)
typedef __attribute__((ext_vector_type(4))) float f4v;   // MFMA accumulator
typedef _Float16 h8 __attribute__((ext_vector_type(8))); // 8 x f16 (4 VGPRs)
typedef unsigned short u16;
typedef unsigned long long u64;

#define DM 512
#define NH 8
#define HD 64
#define BB 4
#define NN 2048

extern "C" __device__ float __ocml_native_exp2_f32(float);
__device__ __forceinline__ float fexp2(float x){ return __ocml_native_exp2_f32(x); }

__device__ __forceinline__ float bf2f(u16 x){ return __uint_as_float(((unsigned)x)<<16); }
__device__ __forceinline__ u16 f2bf(float f){
  unsigned u = __float_as_uint(f);
  u += 0x7FFFu + ((u>>16)&1u);            // round-to-nearest-even
  return (u16)(u>>16);
}
// async global->LDS, 16B per lane; LDS dest = wave-uniform base + lane*16
__device__ __forceinline__ void gl2lds16(const u16* g, u16* l){
  __builtin_amdgcn_global_load_lds((__attribute__((address_space(1))) void*)(g),
                                   (__attribute__((address_space(3))) void*)(l), 16, 0, 0);
}

// ---------------------------------------------------------------------------
// Kernel 1: maskpack, fat blocks. allowed iff M==1. 4096 blocks x 64 words.
// ---------------------------------------------------------------------------
__global__ __launch_bounds__(256) void k_maskpack(const int* M, u64* bits){
  int tid = threadIdx.x;
  int wv = tid>>6, lane = tid&63;
  size_t w0 = (size_t)blockIdx.x*64 + wv*16;
  #pragma unroll
  for (int it=0; it<16; it++){
    int v = M[(w0+it)*64 + lane];
    u64 bal = __ballot(v == 1);
    if (lane == 0) bits[w0+it] = bal;
  }
}

// ---------------------------------------------------------------------------
// Kernel 2: prep = weight permute/convert (blk<2049) + mask tile-AND (rest).
// Runs after k_maskpack (needs bits).
// ---------------------------------------------------------------------------
__global__ void k_prep(const float* Wq, const float* bq, const float* Wk, const float* bk,
                       const float* Wv, const float* bv, const float* Wm,
                       u16* Wp, u16* Wmp, float* bp,
                       const u64* bits, u64* allw){
  int blk = blockIdx.x, tid = threadIdx.x;
  if (blk < 1536){
    int t = blk >> 9, op = blk & 511;
    int srow = ((op & 63) << 3) | (op >> 6);
    const float* W = (t==0) ? Wq : ((t==1) ? Wk : Wv);
    for (int j = tid; j < 512; j += 256)
      Wp[((size_t)t*512 + op)*512 + j] = f2bf(W[(size_t)srow*512 + j]);
  } else if (blk < 2048){
    int o = blk - 1536;
    for (int c = tid; c < 512; c += 256){
      int scol = ((c & 63) << 3) | (c >> 6);
      Wmp[(size_t)o*512 + c] = f2bf(Wm[(size_t)o*512 + scol]);
    }
  } else if (blk == 2048){
    for (int idx = tid; idx < 1536; idx += 256){
      int t = idx >> 9, op = idx & 511;
      const float* bs = (t==0) ? bq : ((t==1) ? bk : bv);
      int srow = ((op & 63) << 3) | (op >> 6);
      bp[idx] = bs[srow];
    }
  } else {
    __shared__ u64 red[256];
    int bnt = blk - 2049;
    int mt = tid & 31, rg = tid >> 5;
    const u64* base = bits + (size_t)bnt*64*32;
    u64 v = ~0ull;
    #pragma unroll
    for (int j=0;j<8;j++) v &= base[(size_t)(rg*8+j)*32 + mt];
    red[tid] = v;
    __syncthreads();
    if (tid < 32){
      u64 a = red[tid];
      #pragma unroll
      for (int g2=1; g2<8; g2++) a &= red[g2*32 + tid];
      allw[(size_t)bnt*32 + tid] = a;
    }
  }
}

// ---------------------------------------------------------------------------
// Kernel 3: transpose + convert inputs  f32 [b][i][r] -> bf16 XT[t][b][r][i]
// ---------------------------------------------------------------------------
__global__ __launch_bounds__(256) void k_transpose(const float* q, const float* k, const float* v, u16* XT){
  __shared__ u16 T[64*72];
  int blk = blockIdx.x, tid = threadIdx.x;
  int rt = blk & 31; blk >>= 5;
  int it = blk & 7;  blk >>= 3;
  int b  = blk & 3;  int t = blk >> 2;
  const float* src = (t==0) ? q : ((t==1) ? k : v);
  src += (size_t)b*DM*NN;
  int i0 = it*64, r0 = rt*64;
  int il = tid>>4, rj = (tid&15)*4;
  #pragma unroll
  for (int p=0;p<4;p++){
    int i = il + p*16;
    float4 vv = *(const float4*)&src[(size_t)(i0+i)*NN + r0 + rj];
    float fv[4] = {vv.x, vv.y, vv.z, vv.w};
    #pragma unroll
    for (int qq=0;qq<4;qq++){
      int r = rj + qq;
      int sr = ((r&3)<<4) | (r>>2);
      T[sr*72 + i] = f2bf(fv[qq]);
    }
  }
  __syncthreads();
  u16* dst = XT + ((size_t)(t*4+b)*NN)*DM;
  int rl = tid>>3, ib = (tid&7)*8;
  #pragma unroll
  for (int p=0;p<2;p++){
    int r = rl + p*32;
    int sr = ((r&3)<<4) | (r>>2);
    s8v vv = *(s8v*)&T[sr*72 + ib];
    *(s8v*)&dst[(size_t)(r0+r)*DM + i0 + ib] = vv;
  }
}

// ---------------------------------------------------------------------------
// Kernel 4: projection GEMM, m97-style 128x128 tile, BK=32, global_load_lds.
// Block swizzle: nt = blk/192, mt = blk%192 -> the 4 nt-blocks sharing an
// A-tile have IDs stride 192 (== 0 mod 8) -> SAME XCD -> A-tile fetched from
// HBM once per XCD instead of 4x.
// t=0 (Q, scaled log2e/8) / t=1 (K) -> P[t*4+b][h][r][d] bf16
// t=2 (V) -> VT[b][h][mp][w][d][lq][8] f16, K=32-fragment-native permuted
//            layout for the flash PV mfma_f32_16x16x32_f16.
// ---------------------------------------------------------------------------
__global__ __launch_bounds__(256) void k_proj(const u16* XT, const u16* Wp, const float* bp,
                                              u16* P, u16* VT){
  __shared__ u16 Al[128*32];
  __shared__ u16 Bl[128*32];
  __shared__ u16 S[128*72];
  int blk = blockIdx.x, tid = threadIdx.x;
  int nt = blk / 192; int mt = blk % 192;   // XCD-colocating decode
  int tb = mt >> 4;                         // t*4+b
  int t  = tb >> 2, b = tb & 3;
  int r0 = (mt & 15)*128, o0 = nt*128;
  const u16* Abase = XT + ((size_t)tb*NN + r0)*DM;
  const u16* Bbase = Wp + ((size_t)t*512 + o0)*DM;

  int w = tid>>6, L = tid&63, li = L&15, lq = L>>4;
  int wr = w>>1, wc = w&1;
  int srow = tid>>2;
  int g8   = ((tid&3) ^ ((tid>>3)&3))*8;
  u16* AldsW = &Al[((tid&192))*8];
  u16* BldsW = &Bl[((tid&192))*8];
  int sw = (li>>1)&3;

  f4v acc[4][4];
  #pragma unroll
  for (int a=0;a<4;a++)
    #pragma unroll
    for (int c2=0;c2<4;c2++) acc[a][c2] = (f4v){0.f,0.f,0.f,0.f};

  for (int kk=0; kk<16; kk++){
    int k0 = kk*32;
    __syncthreads();
    #pragma unroll
    for (int c=0;c<2;c++){
      gl2lds16(&Abase[(size_t)(srow + c*64)*DM + k0 + g8], AldsW + c*2048);
      gl2lds16(&Bbase[(size_t)(srow + c*64)*DM + k0 + g8], BldsW + c*2048);
    }
    __syncthreads();
    s8v af[4], bfr[4];
    #pragma unroll
    for (int a=0;a<4;a++){
      int r = wr*64 + a*16 + li;
      af[a] = *(s8v*)&Al[r*32 + ((lq ^ sw))*8];
    }
    #pragma unroll
    for (int c2=0;c2<4;c2++){
      int r = wc*64 + c2*16 + li;
      bfr[c2] = *(s8v*)&Bl[r*32 + ((lq ^ sw))*8];
    }
    #pragma unroll
    for (int a=0;a<4;a++)
      #pragma unroll
      for (int c2=0;c2<4;c2++)
        acc[a][c2] = __builtin_amdgcn_mfma_f32_16x16x32_bf16(af[a], bfr[c2], acc[a][c2], 0, 0, 0);
  }

  if (t < 2){
    // Q pre-scaled by (1/8)*log2(e) so flash can use exp2 directly
    float scale = (t==0) ? 0.18033688f : 1.0f;
    #pragma unroll
    for (int p=0;p<2;p++){
      if (wc == p){
        #pragma unroll
        for (int c2=0;c2<4;c2++){
          int cl = c2*16 + li;
          float bias = bp[t*512 + o0 + p*64 + cl];
          #pragma unroll
          for (int a=0;a<4;a++)
            #pragma unroll
            for (int ri=0;ri<4;ri++)
              S[(wr*64 + a*16 + lq*4 + ri)*72 + cl] = f2bf((acc[a][c2][ri] + bias)*scale);
        }
      }
      __syncthreads();
      int row = tid>>1, cb = (tid&1)*32;
      int hh = (o0>>6) + p;
      u16* Pb = P + (((size_t)tb*NH + hh)*NN + r0 + row)*HD + cb;
      #pragma unroll
      for (int c=0;c<4;c++){
        s8v vv = *(s8v*)&S[row*72 + cb + c*8];
        *(s8v*)&Pb[c*8] = vv;
      }
      __syncthreads();
    }
  } else {
    // V: f16, permuted K=32-fragment layout.
    // VT element [((b*NH+hh)*16 + mp)*8192 + w2*2048 + d*32 + lq2*8 + t2]
    //   = V[d][ m = mp*128 + (t2>=4)*64 + w2*16 + lq2*4 + (t2&3) ]
    int mp = mt & 15;                        // r0 >> 7
    #pragma unroll
    for (int p=0;p<2;p++){
      if (wc == p){
        #pragma unroll
        for (int c2=0;c2<4;c2++){
          int cl = c2*16 + li;
          float bias = bp[2*512 + o0 + p*64 + cl];
          #pragma unroll
          for (int a=0;a<4;a++)
            #pragma unroll
            for (int ri=0;ri<4;ri++){
              _Float16 hh = (_Float16)(acc[a][c2][ri] + bias);
              S[(wr*64 + a*16 + lq*4 + ri)*72 + cl] = *(const u16*)&hh;
            }
        }
      }
      __syncthreads();
      int hh = (o0>>6) + p;
      u16* Vbw = VT + ((size_t)(b*NH + hh)*16 + mp)*8192;
      #pragma unroll
      for (int it2=0; it2<4; it2++){
        int c = tid + it2*256;            // 0..1023, 8 u16 each
        int w2  = c >> 8;                 // wave slot 0..3
        int d   = (c >> 2) & 63;
        int lq2 = c & 3;
        u16 tmp[8];
        #pragma unroll
        for (int t2=0;t2<8;t2++){
          int ml = ((t2>>2)<<6) + w2*16 + lq2*4 + (t2&3);
          tmp[t2] = S[ml*72 + d];
        }
        *(s8v*)&Vbw[(size_t)w2*2048 + d*32 + lq2*8] = *(s8v*)&tmp[0];
      }
      __syncthreads();
    }
  }
}

// ---------------------------------------------------------------------------
// Kernel 5: transposed-S flash, barrier-free, register pipeline, XCD-local.
// Paired 128-m steps: PV uses full-rate mfma_f32_16x16x32_f16 (K=32) fed by
// the permuted VT layout; exp2 (Q pre-scaled by log2e/8).
// ---------------------------------------------------------------------------
__global__ __launch_bounds__(256) void k_flash(const u16* Pq, const u16* VT, const u64* bits,
                                               const u64* allw, u16* Xout){
  __shared__ __align__(16) char smem[18432 + 1024];
  float* Red = (float*)smem;               // [64][68] f32
  float* lsb = (float*)(smem + 18432);     // [4][64]

  int blk = blockIdx.x, tid = threadIdx.x;
  int bh = blk & 31; int nt = blk >> 5;
  int b = bh >> 3;
  int n0 = nt*64;
  const size_t TSZ = (size_t)BB*NH*NN*HD;
  const u16* Qb = Pq + ((size_t)bh*NN + n0)*HD;
  const u16* Kb = Pq + TSZ + (size_t)bh*NN*HD;
  const u16* Vb = VT + (size_t)bh*NN*HD;          // permuted tiled f16
  const u64* awp = allw + ((size_t)b*32 + nt)*32;

  int w = tid>>6, L = tid&63, li = L&15, lq = L>>4;

  // Q fragments in registers (loop-invariant)
  s8v Qf[4][2];
  #pragma unroll
  for (int j=0;j<4;j++)
    #pragma unroll
    for (int h2=0;h2<2;h2++)
      Qf[j][h2] = *(const s8v*)&Qb[(size_t)(j*16+li)*HD + h2*32 + lq*8];

  f4v O[4][4];     // O^T partial: [d-block j2][n-block j]
  #pragma unroll
  for (int j2=0;j2<4;j2++)
    #pragma unroll
    for (int j=0;j<4;j++) O[j2][j] = (f4v){0.f,0.f,0.f,0.f};
  float ls[4] = {0.f,0.f,0.f,0.f};

  const u16* Krow = Kb + (size_t)(w*16 + li)*HD + lq*8;   // + mp*8192 (+4096 chunk B)
  const u16* Vrow = Vb + (size_t)w*2048 + li*32 + lq*8;   // + mp*8192 + j2*512

  // prefetch mp=0 K (both chunks)
  s8v cKA0 = *(const s8v*)&Krow[0];
  s8v cKA1 = *(const s8v*)&Krow[32];
  s8v cKB0 = *(const s8v*)&Krow[4096];
  s8v cKB1 = *(const s8v*)&Krow[4128];

  int mbit = w*16 + lq*4;

  for (int mp=0; mp<16; mp++){
    // next pair's K (wrap avoids branch; redundant last iter, L2-hit)
    size_t noff = (size_t)((mp+1)&15)*8192;
    s8v nKA0 = *(const s8v*)&Krow[noff];
    s8v nKA1 = *(const s8v*)&Krow[noff + 32];
    s8v nKB0 = *(const s8v*)&Krow[noff + 4096];
    s8v nKB1 = *(const s8v*)&Krow[noff + 4128];
    // this pair's V: issued here, consumed after both QK+exp phases (~L2 lat covered)
    size_t voff = (size_t)mp*8192;
    h8 cV[4];
    #pragma unroll
    for (int j2=0;j2<4;j2++) cV[j2] = *(const h8*)&Vrow[voff + j2*512];

    u64 awA = awp[2*mp], awB = awp[2*mp+1];
    h8 Pf[4];
    f4v S[4];

    // ---- chunk A: m = mp*128 + w*16 + lq*4 + r ----
    __builtin_amdgcn_s_setprio(1);
    #pragma unroll
    for (int j=0;j<4;j++){
      f4v c = (f4v){0.f,0.f,0.f,0.f};
      c = __builtin_amdgcn_mfma_f32_16x16x32_bf16(cKA0, Qf[j][0], c, 0, 0, 0);
      c = __builtin_amdgcn_mfma_f32_16x16x32_bf16(cKA1, Qf[j][1], c, 0, 0, 0);
      S[j] = c;
    }
    __builtin_amdgcn_s_setprio(0);
    if (awA == ~0ull){
      #pragma unroll
      for (int j=0;j<4;j++){
        float e0 = fexp2(S[j][0]), e1 = fexp2(S[j][1]);
        float e2 = fexp2(S[j][2]), e3 = fexp2(S[j][3]);
        ls[j] += (e0+e1)+(e2+e3);
        Pf[j][0] = (_Float16)e0; Pf[j][1] = (_Float16)e1;
        Pf[j][2] = (_Float16)e2; Pf[j][3] = (_Float16)e3;
      }
    } else {
      #pragma unroll
      for (int j=0;j<4;j++){
        u64 mw = bits[((size_t)b*NN + n0 + j*16 + li)*32 + 2*mp];
        float e[4];
        #pragma unroll
        for (int r=0;r<4;r++){
          float ev = fexp2(S[j][r]);
          e[r] = ((mw>>(mbit+r)) & 1ull) ? ev : 0.f;
          Pf[j][r] = (_Float16)e[r];
        }
        ls[j] += (e[0]+e[1])+(e[2]+e[3]);
      }
    }

    // ---- chunk B: m = mp*128 + 64 + w*16 + lq*4 + r ----
    __builtin_amdgcn_s_setprio(1);
    #pragma unroll
    for (int j=0;j<4;j++){
      f4v c = (f4v){0.f,0.f,0.f,0.f};
      c = __builtin_amdgcn_mfma_f32_16x16x32_bf16(cKB0, Qf[j][0], c, 0, 0, 0);
      c = __builtin_amdgcn_mfma_f32_16x16x32_bf16(cKB1, Qf[j][1], c, 0, 0, 0);
      S[j] = c;
    }
    __builtin_amdgcn_s_setprio(0);
    if (awB == ~0ull){
      #pragma unroll
      for (int j=0;j<4;j++){
        float e0 = fexp2(S[j][0]), e1 = fexp2(S[j][1]);
        float e2 = fexp2(S[j][2]), e3 = fexp2(S[j][3]);
        ls[j] += (e0+e1)+(e2+e3);
        Pf[j][4] = (_Float16)e0; Pf[j][5] = (_Float16)e1;
        Pf[j][6] = (_Float16)e2; Pf[j][7] = (_Float16)e3;
      }
    } else {
      #pragma unroll
      for (int j=0;j<4;j++){
        u64 mw = bits[((size_t)b*NN + n0 + j*16 + li)*32 + 2*mp + 1];
        float e[4];
        #pragma unroll
        for (int r=0;r<4;r++){
          float ev = fexp2(S[j][r]);
          e[r] = ((mw>>(mbit+r)) & 1ull) ? ev : 0.f;
          Pf[j][4+r] = (_Float16)e[r];
        }
        ls[j] += (e[0]+e[1])+(e[2]+e[3]);
      }
    }

    // O^T += V^T P, full-rate K=32 f16 MFMA (all operands in registers)
    __builtin_amdgcn_s_setprio(1);
    #pragma unroll
    for (int j2=0;j2<4;j2++)
      #pragma unroll
      for (int j=0;j<4;j++)
        O[j2][j] = __builtin_amdgcn_mfma_f32_16x16x32_f16(cV[j2], Pf[j], O[j2][j], 0, 0, 0);
    __builtin_amdgcn_s_setprio(0);

    cKA0 = nKA0; cKA1 = nKA1; cKB0 = nKB0; cKB1 = nKB1;
  }

  // reduce ls over lq (lanes li, li+16, li+32, li+48)
  #pragma unroll
  for (int j=0;j<4;j++){
    float r = ls[j];
    r += __shfl_xor(r, 16); r += __shfl_xor(r, 32);
    ls[j] = r;
  }
  if (lq == 0){
    #pragma unroll
    for (int j=0;j<4;j++) lsb[w*64 + j*16 + li] = ls[j];
  }
  __syncthreads();

  // cross-wave O^T reduction into Red[n][d] (4 phases)
  #pragma unroll
  for (int ph=0; ph<4; ph++){
    if (w == ph){
      #pragma unroll
      for (int j=0;j<4;j++)
        #pragma unroll
        for (int j2=0;j2<4;j2++){
          f4v* p = (f4v*)&Red[(j*16+li)*68 + j2*16 + lq*4];
          if (ph == 0) *p = O[j2][j];
          else { f4v t = *p; t += O[j2][j]; *p = t; }
        }
    }
    __syncthreads();
  }

  // normalize + write Xout[b][n][h*64+d]
  int n = tid>>2, d0 = (tid&3)*16;
  float s = lsb[n] + lsb[64+n] + lsb[128+n] + lsb[192+n];
  float inv = (s > 0.f) ? 1.0f/s : 0.f;
  int h = bh & 7;
  u16* Xo = Xout + ((size_t)b*NN + n0 + n)*DM + h*HD + d0;
  u16 tmp[16];
  #pragma unroll
  for (int e2=0;e2<4;e2++){
    f4v vv = *(f4v*)&Red[n*68 + d0 + e2*4];
    #pragma unroll
    for (int q2=0;q2<4;q2++) tmp[e2*4+q2] = f2bf(vv[q2]*inv);
  }
  *(s8v*)&Xo[0] = *(s8v*)&tmp[0];
  *(s8v*)&Xo[8] = *(s8v*)&tmp[8];
}

// ---------------------------------------------------------------------------
// Kernel 6: output GEMM, 64(o) x 128(n) tiles -> 512 blocks (2/CU).
// A=Wmp (o rows), B=Xout (n rows). out[b][o][n] = acc + bm[o] (f32)
// ---------------------------------------------------------------------------
__global__ __launch_bounds__(256) void k_out(const u16* Wmp, const u16* Xout, const float* bm, float* out){
  __shared__ u16 Al[64*32];
  __shared__ u16 Bl[128*32];
  int blk = blockIdx.x, tid = threadIdx.x;
  int nt = blk & 15; blk >>= 4;
  int ot = blk & 7;  int b = blk >> 3;
  int o0 = ot*64, n0 = nt*128;
  const u16* Abase = Wmp + (size_t)o0*DM;
  const u16* Bbase = Xout + ((size_t)b*NN + n0)*DM;

  int w = tid>>6, L = tid&63, li = L&15, lq = L>>4;
  int wo = w&1, wn = w>>1;
  int srow = tid>>2;
  int g8   = ((tid&3) ^ ((tid>>3)&3))*8;
  u16* AldsW = &Al[((tid&192))*8];
  u16* BldsW = &Bl[((tid&192))*8];
  int sw = (li>>1)&3;

  f4v acc[2][4];
  #pragma unroll
  for (int a=0;a<2;a++)
    #pragma unroll
    for (int c2=0;c2<4;c2++) acc[a][c2] = (f4v){0.f,0.f,0.f,0.f};

  for (int kk=0; kk<16; kk++){
    int k0 = kk*32;
    __syncthreads();
    gl2lds16(&Abase[(size_t)srow*DM + k0 + g8], AldsW);
    #pragma unroll
    for (int c=0;c<2;c++)
      gl2lds16(&Bbase[(size_t)(srow + c*64)*DM + k0 + g8], BldsW + c*2048);
    __syncthreads();
    s8v af[2], bfr[4];
    #pragma unroll
    for (int a=0;a<2;a++){
      int r = wo*32 + a*16 + li;
      af[a] = *(s8v*)&Al[r*32 + ((lq ^ sw))*8];
    }
    #pragma unroll
    for (int c2=0;c2<4;c2++){
      int r = wn*64 + c2*16 + li;
      bfr[c2] = *(s8v*)&Bl[r*32 + ((lq ^ sw))*8];
    }
    #pragma unroll
    for (int a=0;a<2;a++)
      #pragma unroll
      for (int c2=0;c2<4;c2++)
        acc[a][c2] = __builtin_amdgcn_mfma_f32_16x16x32_bf16(af[a], bfr[c2], acc[a][c2], 0, 0, 0);
  }

  #pragma unroll
  for (int a=0;a<2;a++){
    #pragma unroll
    for (int ri=0;ri<4;ri++){
      int o = o0 + wo*32 + a*16 + lq*4 + ri;
      float bias = bm[o];
      float* ob = out + ((size_t)b*DM + o)*NN + n0 + wn*64;
      #pragma unroll
      for (int c2=0;c2<4;c2++)
        ob[c2*16 + li] = acc[a][c2][ri] + bias;
    }
  }
}

// ---------------------------------------------------------------------------
extern "C" void kernel_launch(void* const* d_in, const int* in_sizes, int n_in,
                              void* d_out, int out_size, void* d_ws, size_t ws_size,
                              hipStream_t stream){
  const float* q  = (const float*)d_in[0];
  const float* k  = (const float*)d_in[1];
  const float* v  = (const float*)d_in[2];
  const int*   M  = (const int*)d_in[3];
  const float* Wq = (const float*)d_in[4];
  const float* bq = (const float*)d_in[5];
  const float* Wk = (const float*)d_in[6];
  const float* bk = (const float*)d_in[7];
  const float* Wv = (const float*)d_in[8];
  const float* bv = (const float*)d_in[9];
  const float* Wm = (const float*)d_in[10];
  const float* bm = (const float*)d_in[11];

  char* ws = (char*)d_ws;
  u16*   XT   = (u16*)(ws + 0);            // 25,165,824
  u16*   P    = (u16*)(ws + 25165824);     // Q,K: 16,777,216
  u16*   VT   = (u16*)(ws + 41943040);     //  8,388,608 (f16, permuted tiled)
  u16*   Wp   = (u16*)(ws + 50331648);     //  1,572,864
  u16*   Wmp  = (u16*)(ws + 51904512);     //    524,288
  float* bp   = (float*)(ws + 52428800);   //      6,144
  u64*   bits = (u64*)(ws + 52434944);     //  2,097,152
  u16*   Xout = (u16*)(ws + 54532096);     //  8,388,608
  u64*   allw = (u64*)(ws + 62920704);     //     32,768
  float* out  = (float*)d_out;

  k_maskpack<<<4096, 256, 0, stream>>>(M, bits);
  k_prep<<<2177, 256, 0, stream>>>(Wq, bq, Wk, bk, Wv, bv, Wm, Wp, Wmp, bp, bits, allw);
  k_transpose<<<3072, 256, 0, stream>>>(q, k, v, XT);
  k_proj<<<768, 256, 0, stream>>>(XT, Wp, bp, P, VT);
  k_flash<<<1024, 256, 0, stream>>>(P, VT, bits, allw, Xout);
  k_out<<<512, 256, 0, stream>>>(Wmp, Xout, bm, out);
}